// Round 10
// baseline (371.957 us; speedup 1.0000x reference)
//
#include <hip/hip_runtime.h>

#define NUM_USERS 100000
#define NUM_ITEMS 50000
#define N_NODES   150000
#define N_EDGES   2000000
#define DIM       128
#define DIM4      32          // DIM/4 (float4 per row)
#define CH8       16          // DIM/8 (half8 chunks per row)
#define BATCH     4096
#define B_SHIFT   9
#define BUCK_N    (1 << B_SHIFT)                         // 512 nodes/bucket
#define NBUCK     ((N_NODES + BUCK_N - 1) >> B_SHIFT)    // 293
#define CHUNK     8192
#define NCHUNK    ((N_EDGES + CHUNK - 1) / CHUNK)        // 245
#define CAP       12288       // max staged edges per bucket (48 KB LDS)
#define CAPB      16384       // fixed tmp region capacity per bucket

typedef _Float16 half_t;
typedef __attribute__((ext_vector_type(8))) _Float16 half8;

// ---------- pass C: bin edges into fixed bucket regions, packed (src<<9)|(dst&511) ----------
// bcur holds RELATIVE cursors (zeroed by memset); region base = bucket*CAPB.

__global__ void bucket_scatter_kernel(const int* __restrict__ src,
                                      const int* __restrict__ dst,
                                      int* __restrict__ bcur,
                                      int* __restrict__ tmp) {
    __shared__ int lhist[NBUCK];
    __shared__ int lcur[NBUCK];
    int t = threadIdx.x;  // 512
    int base = blockIdx.x * CHUNK;
    for (int i = t; i < NBUCK; i += 512) lhist[i] = 0;
    __syncthreads();
    for (int i = 0; i < CHUNK / 512; ++i) {
        int e = base + i * 512 + t;
        if (e < N_EDGES) atomicAdd(&lhist[dst[e] >> B_SHIFT], 1);
    }
    __syncthreads();
    for (int i = t; i < NBUCK; i += 512) {
        int c = lhist[i];
        lcur[i] = c ? (i * CAPB + atomicAdd(&bcur[i], c)) : 0;
    }
    __syncthreads();
    for (int i = 0; i < CHUNK / 512; ++i) {
        int e = base + i * 512 + t;
        if (e < N_EDGES) {
            int d = dst[e];
            int buck = d >> B_SHIFT;
            int pos = atomicAdd(&lcur[buck], 1);
            if (pos < (buck + 1) * CAPB)  // overflow guard (statistically unreachable)
                tmp[pos] = (src[e] << B_SHIFT) | (d & (BUCK_N - 1));
        }
    }
}

// ---------- pass D: prefix + local hist/scan + counting sort + fp16 conv of own rows ----------
// Emits row_start / rinv / sdeg / csr_src / e16. 512 threads. 56 KB LDS.

__global__ void place_conv_kernel(const int* __restrict__ bcur,
                                  const int* __restrict__ tmp,
                                  const float4* __restrict__ ue4,
                                  const float4* __restrict__ ie4,
                                  int* __restrict__ row_start,
                                  float* __restrict__ rinv,
                                  float* __restrict__ sdeg,
                                  int* __restrict__ csr_src,
                                  half8* __restrict__ e16) {
    __shared__ int   lhist[BUCK_N];
    __shared__ int   lofs[BUCK_N];
    __shared__ int   ssc[512];
    __shared__ float rf[BUCK_N];
    __shared__ int   outbuf[CAP];
    int b = blockIdx.x;
    int t = threadIdx.x;  // 512

    // global exclusive prefix over clamped bucket counts (293 values)
    int c = 0;
    if (t < NBUCK) {
        c = bcur[t];
        if (c > CAPB) c = CAPB;
    }
    ssc[t] = c;
    __syncthreads();
    for (int off = 1; off < 512; off <<= 1) {
        int v = (t >= off) ? ssc[t - off] : 0;
        __syncthreads();
        ssc[t] += v;
        __syncthreads();
    }
    int beg = (b == 0) ? 0 : ssc[b - 1];
    int end = ssc[b];
    int cnt = end - beg;
    int tbase = b * CAPB;
    int n0 = b << B_SHIFT;
    int n1 = n0 + BUCK_N; if (n1 > N_NODES) n1 = N_NODES;
    if (b == NBUCK - 1 && t == 0) row_start[N_NODES] = end;

    lhist[t] = 0;
    __syncthreads();
    for (int e = t; e < cnt; e += 512)
        atomicAdd(&lhist[tmp[tbase + e] & (BUCK_N - 1)], 1);
    __syncthreads();

    // 512-wide exclusive scan of per-row degrees
    int v = lhist[t];
    ssc[t] = v;
    __syncthreads();
    for (int off = 1; off < 512; off <<= 1) {
        int u = (t >= off) ? ssc[t - off] : 0;
        __syncthreads();
        ssc[t] += u;
        __syncthreads();
    }
    int excl = ssc[t] - v;
    lofs[t] = excl;
    {
        float d = (float)(v > 1 ? v : 1);
        float rr = rsqrtf(d);
        rf[t] = rr;
        int node = n0 + t;
        if (node < n1) {
            row_start[node] = beg + excl;
            rinv[node] = rr;
            sdeg[node] = d * rr;  // sqrt(d)
        }
    }
    __syncthreads();

    // counting sort into LDS, then coalesced write-out
    if (cnt <= CAP) {
        for (int e = t; e < cnt; e += 512) {
            int p = tmp[tbase + e];
            int pos = atomicAdd(&lofs[p & (BUCK_N - 1)], 1);
            outbuf[pos] = p >> B_SHIFT;
        }
        __syncthreads();
        for (int i = t; i < cnt; i += 512) csr_src[beg + i] = outbuf[i];
    } else {
        for (int e = t; e < cnt; e += 512) {
            int p = tmp[tbase + e];
            int pos = atomicAdd(&lofs[p & (BUCK_N - 1)], 1);
            csr_src[beg + pos] = p >> B_SHIFT;
        }
    }

    // fp16 conversion of this bucket's rows: e16[n] = fp16(rinv[n] * emb[n])
    int nrows = n1 - n0;
    for (int idx = t; idx < nrows * CH8; idx += 512) {
        int r = idx >> 4;
        int j = idx & 15;
        int node = n0 + r;
        const float4* row = (node < NUM_USERS) ? ue4 + (size_t)node * DIM4
                                               : ie4 + (size_t)(node - NUM_USERS) * DIM4;
        float rr = rf[r];
        float4 f0 = row[2 * j];
        float4 f1 = row[2 * j + 1];
        half8 h;
        h[0] = (half_t)(rr * f0.x); h[1] = (half_t)(rr * f0.y);
        h[2] = (half_t)(rr * f0.z); h[3] = (half_t)(rr * f0.w);
        h[4] = (half_t)(rr * f1.x); h[5] = (half_t)(rr * f1.y);
        h[6] = (half_t)(rr * f1.z); h[7] = (half_t)(rr * f1.w);
        e16[(size_t)node * CH8 + j] = h;
    }
}

// ---------- mark + compact list of rows needing w2 (batch nodes + neighbors) ----------
// 512 blocks x 256 threads; 16 elems/block, 16 lanes/elem.

__global__ void mark_list_kernel(const int* __restrict__ users,
                                 const int* __restrict__ items,
                                 const int* __restrict__ row_start,
                                 const int* __restrict__ csr_src,
                                 int* __restrict__ mark,
                                 int* __restrict__ list,
                                 int* __restrict__ nmarked) {
    int g = threadIdx.x >> 4;
    int lane = threadIdx.x & 15;
    int b = blockIdx.x * 16 + g;  // 0..2*BATCH-1
    int node = (b < BATCH) ? users[b] : (NUM_USERS + items[b - BATCH]);
    if (lane == 0) {
        if (atomicExch(&mark[node], 1) == 0)
            list[atomicAdd(nmarked, 1)] = node;
    }
    int beg = row_start[node], end = row_start[node + 1];
    for (int e = beg + lane; e < end; e += 16) {
        int s = csr_src[e];
        if (atomicExch(&mark[s], 1) == 0)
            list[atomicAdd(nmarked, 1)] = s;
    }
}

// ---------- SpMM layer 1 (all rows): out[n] = fp16(rinv[n]^2 * sum_s in[s]) ----------

__global__ void spmm16_kernel(const half8* __restrict__ in16,
                              const int* __restrict__ row_start,
                              const int* __restrict__ csr_src,
                              const float* __restrict__ rinv,
                              half8* __restrict__ out16) {
    int g = threadIdx.x >> 4;
    int lane = threadIdx.x & 15;
    int n = blockIdx.x * 16 + g;
    if (n >= N_NODES) return;
    int beg = row_start[n], end = row_start[n + 1];
    float a[8];
#pragma unroll
    for (int j = 0; j < 8; ++j) a[j] = 0.f;
    int e = beg;
    for (; e + 4 <= end; e += 4) {
        int s0 = csr_src[e], s1 = csr_src[e + 1], s2 = csr_src[e + 2], s3 = csr_src[e + 3];
        half8 h0 = in16[(size_t)s0 * CH8 + lane];
        half8 h1 = in16[(size_t)s1 * CH8 + lane];
        half8 h2 = in16[(size_t)s2 * CH8 + lane];
        half8 h3 = in16[(size_t)s3 * CH8 + lane];
#pragma unroll
        for (int j = 0; j < 8; ++j)
            a[j] += ((float)h0[j] + (float)h1[j]) + ((float)h2[j] + (float)h3[j]);
    }
    for (; e < end; ++e) {
        int s0 = csr_src[e];
        half8 h0 = in16[(size_t)s0 * CH8 + lane];
#pragma unroll
        for (int j = 0; j < 8; ++j) a[j] += (float)h0[j];
    }
    float f = rinv[n]; f *= f;
    half8 o;
#pragma unroll
    for (int j = 0; j < 8; ++j) o[j] = (half_t)(a[j] * f);
    out16[(size_t)n * CH8 + lane] = o;
}

// ---------- SpMM layer 2 over compacted row list ----------

__global__ void spmm16_list_kernel(const half8* __restrict__ in16,
                                   const int* __restrict__ row_start,
                                   const int* __restrict__ csr_src,
                                   const float* __restrict__ rinv,
                                   const int* __restrict__ list,
                                   const int* __restrict__ nmarked,
                                   half8* __restrict__ out16) {
    int g = threadIdx.x >> 4;
    int lane = threadIdx.x & 15;
    int i = blockIdx.x * 16 + g;
    if (i >= *nmarked) return;
    int n = list[i];
    int beg = row_start[n], end = row_start[n + 1];
    float a[8];
#pragma unroll
    for (int j = 0; j < 8; ++j) a[j] = 0.f;
    int e = beg;
    for (; e + 4 <= end; e += 4) {
        int s0 = csr_src[e], s1 = csr_src[e + 1], s2 = csr_src[e + 2], s3 = csr_src[e + 3];
        half8 h0 = in16[(size_t)s0 * CH8 + lane];
        half8 h1 = in16[(size_t)s1 * CH8 + lane];
        half8 h2 = in16[(size_t)s2 * CH8 + lane];
        half8 h3 = in16[(size_t)s3 * CH8 + lane];
#pragma unroll
        for (int j = 0; j < 8; ++j)
            a[j] += ((float)h0[j] + (float)h1[j]) + ((float)h2[j] + (float)h3[j]);
    }
    for (; e < end; ++e) {
        int s0 = csr_src[e];
        half8 h0 = in16[(size_t)s0 * CH8 + lane];
#pragma unroll
        for (int j = 0; j < 8; ++j) a[j] += (float)h0[j];
    }
    float f = rinv[n]; f *= f;
    half8 o;
#pragma unroll
    for (int j = 0; j < 8; ++j) o[j] = (half_t)(a[j] * f);
    out16[(size_t)n * CH8 + lane] = o;
}

// ---------- fused epilogue: acc = emb0 + sdeg*(w1+w2) + rinv*sum_N w2; dot ----------
// 128 threads = 4 batch elems x (2 nodes x 16 lanes). Lane owns 8 channels.

__global__ void epilogue_kernel(const float4* __restrict__ ue4,
                                const float4* __restrict__ ie4,
                                const half8* __restrict__ w1,
                                const half8* __restrict__ w2,
                                const int* __restrict__ row_start,
                                const int* __restrict__ csr_src,
                                const float* __restrict__ rinv,
                                const float* __restrict__ sdeg,
                                const int* __restrict__ users,
                                const int* __restrict__ items,
                                float* __restrict__ out) {
    int t = threadIdx.x;
    int elem = blockIdx.x * 4 + (t >> 5);
    int half = (t >> 4) & 1;
    int lane = t & 15;
    int node = half ? (NUM_USERS + items[elem]) : users[elem];

    const float4* erow = (node < NUM_USERS) ? ue4 + (size_t)node * DIM4
                                            : ie4 + (size_t)(node - NUM_USERS) * DIM4;
    float4 f0 = erow[2 * lane];
    float4 f1 = erow[2 * lane + 1];
    float a[8] = {f0.x, f0.y, f0.z, f0.w, f1.x, f1.y, f1.z, f1.w};

    float sd = sdeg[node];
    half8 h1 = w1[(size_t)node * CH8 + lane];
    half8 h2 = w2[(size_t)node * CH8 + lane];
#pragma unroll
    for (int j = 0; j < 8; ++j) a[j] += sd * ((float)h1[j] + (float)h2[j]);

    int beg = row_start[node], end = row_start[node + 1];
    float a3[8];
#pragma unroll
    for (int j = 0; j < 8; ++j) a3[j] = 0.f;
    int e = beg;
    for (; e + 2 <= end; e += 2) {
        int s0 = csr_src[e], s1 = csr_src[e + 1];
        half8 g0 = w2[(size_t)s0 * CH8 + lane];
        half8 g1 = w2[(size_t)s1 * CH8 + lane];
#pragma unroll
        for (int j = 0; j < 8; ++j) a3[j] += (float)g0[j] + (float)g1[j];
    }
    if (e < end) {
        int s0 = csr_src[e];
        half8 g0 = w2[(size_t)s0 * CH8 + lane];
#pragma unroll
        for (int j = 0; j < 8; ++j) a3[j] += (float)g0[j];
    }
    float rv = rinv[node];
#pragma unroll
    for (int j = 0; j < 8; ++j) a[j] += rv * a3[j];

    int wl = t & 63;
    float p = 0.f;
#pragma unroll
    for (int j = 0; j < 8; ++j) p += a[j] * __shfl(a[j], wl ^ 16, 64);
    for (int off = 8; off > 0; off >>= 1) p += __shfl_down(p, off, 16);
    if (half == 0 && lane == 0) out[elem] = p * (1.0f / 16.0f);
}

extern "C" void kernel_launch(void* const* d_in, const int* in_sizes, int n_in,
                              void* d_out, int out_size, void* d_ws, size_t ws_size,
                              hipStream_t stream) {
    const float4* ue4 = (const float4*)d_in[0];
    const float4* ie4 = (const float4*)d_in[1];
    const int*   src   = (const int*)d_in[2];
    const int*   dst   = (const int*)d_in[3];
    const int*   users = (const int*)d_in[5];
    const int*   items = (const int*)d_in[6];
    float* out = (float*)d_out;

    const size_t h8elems = (size_t)N_NODES * CH8;
    char* ws = (char*)d_ws;
    half8* e16       = (half8*)ws;  ws += h8elems * sizeof(half8);
    half8* w1        = (half8*)ws;  ws += h8elems * sizeof(half8);
    half8* w2        = (half8*)ws;  ws += h8elems * sizeof(half8);
    int*   row_start = (int*)ws;    ws += (size_t)(N_NODES + 1) * sizeof(int);
    float* rinv      = (float*)ws;  ws += (size_t)N_NODES * sizeof(float);
    float* sdeg      = (float*)ws;  ws += (size_t)N_NODES * sizeof(float);
    int*   list      = (int*)ws;    ws += (size_t)N_NODES * sizeof(int);
    int*   mark      = (int*)ws;    ws += (size_t)N_NODES * sizeof(int);   // zeroed
    int*   bcur      = (int*)ws;    ws += (size_t)NBUCK * sizeof(int);     // zeroed
    int*   nmarked   = (int*)ws;    ws += sizeof(int);                     // zeroed
    ws = (char*)(((size_t)ws + 255) & ~(size_t)255);
    int*   tmp       = (int*)ws;    ws += (size_t)NBUCK * CAPB * sizeof(int);
    int*   csr_src   = (int*)ws;    ws += (size_t)N_EDGES * sizeof(int);

    // one memset covers mark + bcur + nmarked (contiguous)
    hipMemsetAsync(mark, 0, ((size_t)N_NODES + NBUCK + 1) * sizeof(int), stream);

    // --- binned CSR build + fused fp16 table ---
    bucket_scatter_kernel<<<NCHUNK, 512, 0, stream>>>(src, dst, bcur, tmp);
    place_conv_kernel<<<NBUCK, 512, 0, stream>>>(
        bcur, tmp, ue4, ie4, row_start, rinv, sdeg, csr_src, e16);

    // --- mark + compact list of rows needing w2 ---
    mark_list_kernel<<<2 * BATCH / 16, 256, 0, stream>>>(
        users, items, row_start, csr_src, mark, list, nmarked);

    // --- layer 1 (all rows) ---
    spmm16_kernel<<<(N_NODES + 15) / 16, 256, 0, stream>>>(e16, row_start, csr_src, rinv, w1);

    // --- layer 2 (compacted marked rows) ---
    spmm16_list_kernel<<<(N_NODES + 15) / 16, 256, 0, stream>>>(
        w1, row_start, csr_src, rinv, list, nmarked, w2);

    // --- fused epilogue: layers 0-3 at batch rows + dot ---
    epilogue_kernel<<<BATCH / 4, 128, 0, stream>>>(
        ue4, ie4, w1, w2, row_start, csr_src, rinv, sdeg, users, items, out);
}

// Round 11
// 306.255 us; speedup vs baseline: 1.2145x; 1.2145x over previous
//
#include <hip/hip_runtime.h>

#define NUM_USERS 100000
#define NUM_ITEMS 50000
#define N_NODES   150000
#define N_EDGES   2000000
#define DIM       128
#define DIM4      32          // DIM/4 (float4 per row)
#define CH8       16          // DIM/8 (half8 chunks per row)
#define BATCH     4096
#define B_SHIFT   9
#define BUCK_N    (1 << B_SHIFT)                         // 512 nodes/bucket
#define NBUCK     ((N_NODES + BUCK_N - 1) >> B_SHIFT)    // 293
#define CHUNK     8192
#define NCHUNK    ((N_EDGES + CHUNK - 1) / CHUNK)        // 245
#define CAP       12288       // max staged edges per bucket (48 KB LDS)
#define CAPB      16384       // fixed tmp region capacity per bucket
#define MARK_BLOCKS 512       // 2*BATCH / 16 elems per 256-thread block
#define CONV_BLOCKS ((N_NODES * CH8 + 255) / 256)        // 9375

typedef _Float16 half_t;
typedef __attribute__((ext_vector_type(8))) _Float16 half8;

// ---------- pass C: bin edges into fixed bucket regions via LDS counting sort ----------
// bcur holds RELATIVE cursors (zeroed by memset); region base = bucket*CAPB.
// Writes to tmp are per-wave coalesced bucket runs, not per-edge scatters.

__global__ void bucket_scatter_kernel(const int* __restrict__ src,
                                      const int* __restrict__ dst,
                                      int* __restrict__ bcur,
                                      int* __restrict__ tmp) {
    __shared__ int lhist[NBUCK];
    __shared__ int lofs[NBUCK];
    __shared__ int lcur[NBUCK];
    __shared__ int gbase[NBUCK];
    __shared__ int ssc[512];
    __shared__ int sorted[CHUNK];   // 32 KB staging
    int t = threadIdx.x;  // 512
    int base = blockIdx.x * CHUNK;
    int nedge = N_EDGES - base; if (nedge > CHUNK) nedge = CHUNK;

    for (int i = t; i < NBUCK; i += 512) lhist[i] = 0;
    __syncthreads();
    for (int i = t; i < nedge; i += 512)
        atomicAdd(&lhist[dst[base + i] >> B_SHIFT], 1);
    __syncthreads();

    // exclusive scan over NBUCK counts (NBUCK < 512)
    int c = (t < NBUCK) ? lhist[t] : 0;
    ssc[t] = c;
    __syncthreads();
    for (int off = 1; off < 512; off <<= 1) {
        int v = (t >= off) ? ssc[t - off] : 0;
        __syncthreads();
        ssc[t] += v;
        __syncthreads();
    }
    if (t < NBUCK) {
        int excl = ssc[t] - c;
        lofs[t] = excl;
        lcur[t] = excl;
        gbase[t] = c ? (t * CAPB + atomicAdd(&bcur[t], c)) : 0;
    }
    __syncthreads();

    // counting sort into LDS
    for (int i = t; i < nedge; i += 512) {
        int d = dst[base + i];
        int b = d >> B_SHIFT;
        int pos = atomicAdd(&lcur[b], 1);
        sorted[pos] = (src[base + i] << B_SHIFT) | (d & (BUCK_N - 1));
    }
    __syncthreads();

    // per-wave coalesced write-out of bucket runs
    int wave = t >> 6, lane = t & 63;
    for (int b = wave; b < NBUCK; b += 8) {
        int cb = lhist[b];
        if (!cb) continue;
        int lo = lofs[b];
        int gb = gbase[b];
        int room = (b + 1) * CAPB - gb;   // overflow guard (statistically unreachable)
        int wcnt = cb < room ? cb : room;
        for (int l = lane; l < wcnt; l += 64)
            tmp[gb + l] = sorted[lo + l];
    }
}

// ---------- pass D: global prefix + local hist/scan + counting sort ----------
// Emits row_start / rinv / sdeg / csr_src. 512 threads.

__global__ void place_kernel(const int* __restrict__ bcur,
                             const int* __restrict__ tmp,
                             int* __restrict__ row_start,
                             float* __restrict__ rinv,
                             float* __restrict__ sdeg,
                             int* __restrict__ csr_src) {
    __shared__ int lhist[BUCK_N];
    __shared__ int lofs[BUCK_N];
    __shared__ int ssc[512];
    __shared__ int outbuf[CAP];
    int b = blockIdx.x;
    int t = threadIdx.x;  // 512

    // global exclusive prefix over clamped bucket counts (293 values)
    int c = 0;
    if (t < NBUCK) {
        c = bcur[t];
        if (c > CAPB) c = CAPB;
    }
    ssc[t] = c;
    __syncthreads();
    for (int off = 1; off < 512; off <<= 1) {
        int v = (t >= off) ? ssc[t - off] : 0;
        __syncthreads();
        ssc[t] += v;
        __syncthreads();
    }
    int beg = (b == 0) ? 0 : ssc[b - 1];
    int end = ssc[b];
    int cnt = end - beg;
    int tbase = b * CAPB;
    int n0 = b << B_SHIFT;
    int n1 = n0 + BUCK_N; if (n1 > N_NODES) n1 = N_NODES;
    if (b == NBUCK - 1 && t == 0) row_start[N_NODES] = end;

    lhist[t] = 0;
    __syncthreads();
    for (int e = t; e < cnt; e += 512)
        atomicAdd(&lhist[tmp[tbase + e] & (BUCK_N - 1)], 1);
    __syncthreads();

    // 512-wide exclusive scan of per-row degrees
    int v = lhist[t];
    ssc[t] = v;
    __syncthreads();
    for (int off = 1; off < 512; off <<= 1) {
        int u = (t >= off) ? ssc[t - off] : 0;
        __syncthreads();
        ssc[t] += u;
        __syncthreads();
    }
    int excl = ssc[t] - v;
    lofs[t] = excl;
    int node = n0 + t;
    if (node < n1) {
        row_start[node] = beg + excl;
        float d = (float)(v > 1 ? v : 1);
        float rr = rsqrtf(d);
        rinv[node] = rr;
        sdeg[node] = d * rr;  // sqrt(d)
    }
    __syncthreads();

    // counting sort into LDS, then coalesced write-out
    if (cnt <= CAP) {
        for (int e = t; e < cnt; e += 512) {
            int p = tmp[tbase + e];
            int pos = atomicAdd(&lofs[p & (BUCK_N - 1)], 1);
            outbuf[pos] = p >> B_SHIFT;
        }
        __syncthreads();
        for (int i = t; i < cnt; i += 512) csr_src[beg + i] = outbuf[i];
    } else {
        for (int e = t; e < cnt; e += 512) {
            int p = tmp[tbase + e];
            int pos = atomicAdd(&lofs[p & (BUCK_N - 1)], 1);
            csr_src[beg + pos] = p >> B_SHIFT;
        }
    }
}

// ---------- fused: mark (batch nodes + neighbors) | fp16 pre-scaled table ----------

__global__ void mark_conv_kernel(const float4* __restrict__ ue4,
                                 const float4* __restrict__ ie4,
                                 const float* __restrict__ rinv,
                                 half8* __restrict__ e16,
                                 const int* __restrict__ users,
                                 const int* __restrict__ items,
                                 const int* __restrict__ row_start,
                                 const int* __restrict__ csr_src,
                                 int* __restrict__ mark) {
    int bid = blockIdx.x;
    if (bid < MARK_BLOCKS) {
        int g = threadIdx.x >> 4;
        int lane = threadIdx.x & 15;
        int b = bid * 16 + g;  // 0..2*BATCH-1
        int node = (b < BATCH) ? users[b] : (NUM_USERS + items[b - BATCH]);
        if (lane == 0) mark[node] = 1;
        int beg = row_start[node], end = row_start[node + 1];
        for (int e = beg + lane; e < end; e += 16) mark[csr_src[e]] = 1;
        return;
    }
    int i = (bid - MARK_BLOCKS) * 256 + threadIdx.x;  // chunk index
    const int total = N_NODES * CH8;
    if (i >= total) return;
    int n = i >> 4;
    int j = i & 15;
    const float4* row = (n < NUM_USERS) ? ue4 + (size_t)n * DIM4
                                        : ie4 + (size_t)(n - NUM_USERS) * DIM4;
    float r = rinv[n];
    float4 f0 = row[2 * j];
    float4 f1 = row[2 * j + 1];
    half8 h;
    h[0] = (half_t)(r * f0.x); h[1] = (half_t)(r * f0.y);
    h[2] = (half_t)(r * f0.z); h[3] = (half_t)(r * f0.w);
    h[4] = (half_t)(r * f1.x); h[5] = (half_t)(r * f1.y);
    h[6] = (half_t)(r * f1.z); h[7] = (half_t)(r * f1.w);
    e16[i] = h;
}

// ---------- SpMM (fp16 rows, fp32 accumulate): out[n] = fp16(rinv[n]^2 * sum_s in[s]) ----------

__global__ void spmm16_kernel(const half8* __restrict__ in16,
                              const int* __restrict__ row_start,
                              const int* __restrict__ csr_src,
                              const float* __restrict__ rinv,
                              half8* __restrict__ out16) {
    int g = threadIdx.x >> 4;
    int lane = threadIdx.x & 15;
    int n = blockIdx.x * 16 + g;
    if (n >= N_NODES) return;
    int beg = row_start[n], end = row_start[n + 1];
    float a[8];
#pragma unroll
    for (int j = 0; j < 8; ++j) a[j] = 0.f;
    int e = beg;
    for (; e + 4 <= end; e += 4) {
        int s0 = csr_src[e], s1 = csr_src[e + 1], s2 = csr_src[e + 2], s3 = csr_src[e + 3];
        half8 h0 = in16[(size_t)s0 * CH8 + lane];
        half8 h1 = in16[(size_t)s1 * CH8 + lane];
        half8 h2 = in16[(size_t)s2 * CH8 + lane];
        half8 h3 = in16[(size_t)s3 * CH8 + lane];
#pragma unroll
        for (int j = 0; j < 8; ++j)
            a[j] += ((float)h0[j] + (float)h1[j]) + ((float)h2[j] + (float)h3[j]);
    }
    for (; e < end; ++e) {
        int s0 = csr_src[e];
        half8 h0 = in16[(size_t)s0 * CH8 + lane];
#pragma unroll
        for (int j = 0; j < 8; ++j) a[j] += (float)h0[j];
    }
    float f = rinv[n]; f *= f;
    half8 o;
#pragma unroll
    for (int j = 0; j < 8; ++j) o[j] = (half_t)(a[j] * f);
    out16[(size_t)n * CH8 + lane] = o;
}

// ---------- masked SpMM: only rows with mark[n]!=0 ----------

__global__ void spmm16_masked_kernel(const half8* __restrict__ in16,
                                     const int* __restrict__ row_start,
                                     const int* __restrict__ csr_src,
                                     const float* __restrict__ rinv,
                                     const int* __restrict__ mark,
                                     half8* __restrict__ out16) {
    int g = threadIdx.x >> 4;
    int lane = threadIdx.x & 15;
    int n = blockIdx.x * 16 + g;
    if (n >= N_NODES) return;
    if (!mark[n]) return;
    int beg = row_start[n], end = row_start[n + 1];
    float a[8];
#pragma unroll
    for (int j = 0; j < 8; ++j) a[j] = 0.f;
    int e = beg;
    for (; e + 4 <= end; e += 4) {
        int s0 = csr_src[e], s1 = csr_src[e + 1], s2 = csr_src[e + 2], s3 = csr_src[e + 3];
        half8 h0 = in16[(size_t)s0 * CH8 + lane];
        half8 h1 = in16[(size_t)s1 * CH8 + lane];
        half8 h2 = in16[(size_t)s2 * CH8 + lane];
        half8 h3 = in16[(size_t)s3 * CH8 + lane];
#pragma unroll
        for (int j = 0; j < 8; ++j)
            a[j] += ((float)h0[j] + (float)h1[j]) + ((float)h2[j] + (float)h3[j]);
    }
    for (; e < end; ++e) {
        int s0 = csr_src[e];
        half8 h0 = in16[(size_t)s0 * CH8 + lane];
#pragma unroll
        for (int j = 0; j < 8; ++j) a[j] += (float)h0[j];
    }
    float f = rinv[n]; f *= f;
    half8 o;
#pragma unroll
    for (int j = 0; j < 8; ++j) o[j] = (half_t)(a[j] * f);
    out16[(size_t)n * CH8 + lane] = o;
}

// ---------- fused epilogue: acc = emb0 + sdeg*(w1+w2) + rinv*sum_N w2; dot ----------
// 128 threads = 4 batch elems x (2 nodes x 16 lanes). Lane owns 8 channels.

__global__ void epilogue_kernel(const float4* __restrict__ ue4,
                                const float4* __restrict__ ie4,
                                const half8* __restrict__ w1,
                                const half8* __restrict__ w2,
                                const int* __restrict__ row_start,
                                const int* __restrict__ csr_src,
                                const float* __restrict__ rinv,
                                const float* __restrict__ sdeg,
                                const int* __restrict__ users,
                                const int* __restrict__ items,
                                float* __restrict__ out) {
    int t = threadIdx.x;
    int elem = blockIdx.x * 4 + (t >> 5);
    int half = (t >> 4) & 1;
    int lane = t & 15;
    int node = half ? (NUM_USERS + items[elem]) : users[elem];

    const float4* erow = (node < NUM_USERS) ? ue4 + (size_t)node * DIM4
                                            : ie4 + (size_t)(node - NUM_USERS) * DIM4;
    float4 f0 = erow[2 * lane];
    float4 f1 = erow[2 * lane + 1];
    float a[8] = {f0.x, f0.y, f0.z, f0.w, f1.x, f1.y, f1.z, f1.w};

    float sd = sdeg[node];
    half8 h1 = w1[(size_t)node * CH8 + lane];
    half8 h2 = w2[(size_t)node * CH8 + lane];
#pragma unroll
    for (int j = 0; j < 8; ++j) a[j] += sd * ((float)h1[j] + (float)h2[j]);

    int beg = row_start[node], end = row_start[node + 1];
    float a3[8];
#pragma unroll
    for (int j = 0; j < 8; ++j) a3[j] = 0.f;
    int e = beg;
    for (; e + 2 <= end; e += 2) {
        int s0 = csr_src[e], s1 = csr_src[e + 1];
        half8 g0 = w2[(size_t)s0 * CH8 + lane];
        half8 g1 = w2[(size_t)s1 * CH8 + lane];
#pragma unroll
        for (int j = 0; j < 8; ++j) a3[j] += (float)g0[j] + (float)g1[j];
    }
    if (e < end) {
        int s0 = csr_src[e];
        half8 g0 = w2[(size_t)s0 * CH8 + lane];
#pragma unroll
        for (int j = 0; j < 8; ++j) a3[j] += (float)g0[j];
    }
    float rv = rinv[node];
#pragma unroll
    for (int j = 0; j < 8; ++j) a[j] += rv * a3[j];

    int wl = t & 63;
    float p = 0.f;
#pragma unroll
    for (int j = 0; j < 8; ++j) p += a[j] * __shfl(a[j], wl ^ 16, 64);
    for (int off = 8; off > 0; off >>= 1) p += __shfl_down(p, off, 16);
    if (half == 0 && lane == 0) out[elem] = p * (1.0f / 16.0f);
}

extern "C" void kernel_launch(void* const* d_in, const int* in_sizes, int n_in,
                              void* d_out, int out_size, void* d_ws, size_t ws_size,
                              hipStream_t stream) {
    const float4* ue4 = (const float4*)d_in[0];
    const float4* ie4 = (const float4*)d_in[1];
    const int*   src   = (const int*)d_in[2];
    const int*   dst   = (const int*)d_in[3];
    const int*   users = (const int*)d_in[5];
    const int*   items = (const int*)d_in[6];
    float* out = (float*)d_out;

    const size_t h8elems = (size_t)N_NODES * CH8;
    char* ws = (char*)d_ws;
    half8* e16       = (half8*)ws;  ws += h8elems * sizeof(half8);
    half8* w1        = (half8*)ws;  ws += h8elems * sizeof(half8);
    half8* w2        = (half8*)ws;  ws += h8elems * sizeof(half8);
    int*   row_start = (int*)ws;    ws += (size_t)(N_NODES + 1) * sizeof(int);
    float* rinv      = (float*)ws;  ws += (size_t)N_NODES * sizeof(float);
    float* sdeg      = (float*)ws;  ws += (size_t)N_NODES * sizeof(float);
    int*   mark      = (int*)ws;    ws += (size_t)N_NODES * sizeof(int);   // zeroed
    int*   bcur      = (int*)ws;    ws += (size_t)NBUCK * sizeof(int);     // zeroed (adjacent)
    ws = (char*)(((size_t)ws + 255) & ~(size_t)255);
    int*   tmp       = (int*)ws;    ws += (size_t)NBUCK * CAPB * sizeof(int);
    int*   csr_src   = (int*)ws;    ws += (size_t)N_EDGES * sizeof(int);

    // one memset covers mark + bcur (contiguous)
    hipMemsetAsync(mark, 0, ((size_t)N_NODES + NBUCK) * sizeof(int), stream);

    // --- binned CSR build ---
    bucket_scatter_kernel<<<NCHUNK, 512, 0, stream>>>(src, dst, bcur, tmp);
    place_kernel<<<NBUCK, 512, 0, stream>>>(bcur, tmp, row_start, rinv, sdeg, csr_src);

    // --- fused mark + fp16 pre-scaled table ---
    mark_conv_kernel<<<MARK_BLOCKS + CONV_BLOCKS, 256, 0, stream>>>(
        ue4, ie4, rinv, e16, users, items, row_start, csr_src, mark);

    // --- layer 1 (all rows) ---
    spmm16_kernel<<<(N_NODES + 15) / 16, 256, 0, stream>>>(e16, row_start, csr_src, rinv, w1);

    // --- layer 2 (marked rows only) ---
    spmm16_masked_kernel<<<(N_NODES + 15) / 16, 256, 0, stream>>>(
        w1, row_start, csr_src, rinv, mark, w2);

    // --- fused epilogue: layers 0-3 at batch rows + dot ---
    epilogue_kernel<<<BATCH / 4, 128, 0, stream>>>(
        ue4, ie4, w1, w2, row_start, csr_src, rinv, sdeg, users, items, out);
}